// Round 7
// baseline (99.851 us; speedup 1.0000x reference)
//
#include <hip/hip_runtime.h>

// MyMarginLoss: loss = sum_{b,m: mask_mentions} [ sum_c (mask_cand & c!=t) *
//                 max(0, 1.5 - (s[t] - s[c])) ] / (C-1)
// B=128, M=256, C=1024, fp32 source, int32 masks (harness-converted).
// Memory-bound: ~134 MB effective traffic at ~5.3 TB/s (50%-dense 4KB-granule
// read pattern ceiling; dense-write fills prove ~7 TB/s on this part).
//
// R7: R2 main body (best: 2048 blocks x 256 thr, 16 rows/block) unchanged.
// Single variable: the separate reduce DISPATCH (~3us node+gap) is replaced
// by an in-kernel two-level threadfence reduction:
//   - 64 group counters on separate 64B lines (32 blocks each: <=256ns
//     serialized per line given the measured ~8ns same-address atomic)
//   - 64 top-counter atomics (~0.5us tail)
//   - last block folds the 2048 partials BLOCK-WIDE (256thr x 8 loads;
//     fixed index order -> deterministic sum), writes d_out.
// Counters zeroed each launch by a small hipMemsetAsync (~2us node, cheaper
// than the reduce-kernel node it replaces). R5 lesson: never >~100 atomics
// on one address.

constexpr int kC = 1024;
constexpr float kMargin = 1.5f;
constexpr int kRowsPerBlock = 16;
constexpr int kBlocks = 2048;              // 32768 rows / 16
constexpr int kGroups = 64;                // 32 blocks per group
constexpr int kCtrStride = 16;             // ints; 64 B between counters

__global__ __launch_bounds__(256)
void margin_kernel(const float* __restrict__ source,
                   const int* __restrict__ target,
                   const int* __restrict__ mask_mentions,
                   const int* __restrict__ mask_candidates,
                   float* __restrict__ partials,
                   int* __restrict__ counters,
                   float* __restrict__ out)
{
    const int lane = threadIdx.x & 63;
    const int wid  = threadIdx.x >> 6;
    const int row0 = blockIdx.x * kRowsPerBlock;

    // chunk metadata, loaded once per wave (redundant across waves; L2-hot)
    int flag = 0, tval = 0;
    if (lane < kRowsPerBlock) {
        flag = mask_mentions[row0 + lane];
        tval = target[row0 + lane];
    }
    const unsigned mask16 = (unsigned)(__ballot(flag != 0) & 0xFFFFull);

    // wave `wid` takes active rows of rank wid, wid+4, wid+8, ...
    unsigned mm = mask16;
    for (int i = 0; i < wid; ++i) mm &= mm - 1;

    float acc = 0.0f;
    while (mm) {
        const int pos = __ffs(mm) - 1;          // this wave's next active row
        #pragma unroll
        for (int k = 0; k < 4; ++k) mm &= mm - 1;  // advance 4 ranks

        const int row = row0 + pos;
        const int t   = __shfl(tval, pos, 64);  // uniform broadcast, no load

        const float4* __restrict__ sp =
            reinterpret_cast<const float4*>(source + (size_t)row * kC);
        const int4*   __restrict__ mp =
            reinterpret_cast<const int4*>(mask_candidates + (size_t)row * kC);

        // 8 independent 1KB-per-wave loads; nothing else touches memory
        const float4 s0 = sp[lane],       s1 = sp[lane + 64],
                     s2 = sp[lane + 128], s3 = sp[lane + 192];
        const int4   m0 = mp[lane],       m1 = mp[lane + 64],
                     m2 = mp[lane + 128], m3 = mp[lane + 192];

        // v_t from registers: elem t lives at rep=t>>8, lane=(t>>2)&63, k=t&3
        const int rep = t >> 8, li = (t >> 2) & 63, kk = t & 3;
        const float4 sr = (rep == 0) ? s0 : (rep == 1) ? s1
                                          : (rep == 2) ? s2 : s3;   // uniform
        const float cand = (kk == 0) ? sr.x : (kk == 1) ? sr.y
                                            : (kk == 2) ? sr.z : sr.w;
        const float base = kMargin - __shfl(cand, li, 64);

        float racc = 0.0f;
        racc += (m0.x != 0) ? fmaxf(0.0f, base + s0.x) : 0.0f;
        racc += (m0.y != 0) ? fmaxf(0.0f, base + s0.y) : 0.0f;
        racc += (m0.z != 0) ? fmaxf(0.0f, base + s0.z) : 0.0f;
        racc += (m0.w != 0) ? fmaxf(0.0f, base + s0.w) : 0.0f;
        racc += (m1.x != 0) ? fmaxf(0.0f, base + s1.x) : 0.0f;
        racc += (m1.y != 0) ? fmaxf(0.0f, base + s1.y) : 0.0f;
        racc += (m1.z != 0) ? fmaxf(0.0f, base + s1.z) : 0.0f;
        racc += (m1.w != 0) ? fmaxf(0.0f, base + s1.w) : 0.0f;
        racc += (m2.x != 0) ? fmaxf(0.0f, base + s2.x) : 0.0f;
        racc += (m2.y != 0) ? fmaxf(0.0f, base + s2.y) : 0.0f;
        racc += (m2.z != 0) ? fmaxf(0.0f, base + s2.z) : 0.0f;
        racc += (m2.w != 0) ? fmaxf(0.0f, base + s2.w) : 0.0f;
        racc += (m3.x != 0) ? fmaxf(0.0f, base + s3.x) : 0.0f;
        racc += (m3.y != 0) ? fmaxf(0.0f, base + s3.y) : 0.0f;
        racc += (m3.z != 0) ? fmaxf(0.0f, base + s3.z) : 0.0f;
        racc += (m3.w != 0) ? fmaxf(0.0f, base + s3.w) : 0.0f;

        // remove the target slot's guaranteed contribution (exactly kMargin)
        if (lane == 0) racc -= kMargin;
        acc += racc;
    }

    // wave-64 butterfly + LDS combine per block
    #pragma unroll
    for (int off = 32; off > 0; off >>= 1)
        acc += __shfl_down(acc, off, 64);

    __shared__ float wsum[4];
    __shared__ int winner;
    if (lane == 0) wsum[wid] = acc;
    __syncthreads();

    if (threadIdx.x == 0) {
        partials[blockIdx.x] = wsum[0] + wsum[1] + wsum[2] + wsum[3];
        __threadfence();                         // release partial
        winner = 0;
        const int g = blockIdx.x >> 5;           // 64 groups of 32 blocks
        if (atomicAdd(&counters[g * kCtrStride], 1) == 31) {
            __threadfence();
            if (atomicAdd(&counters[kGroups * kCtrStride], 1) == kGroups - 1)
                winner = 1;
        }
    }
    __syncthreads();

    if (winner) {                                // exactly one block, last
        __threadfence();                         // acquire (every thread)
        float a = 0.0f;
        #pragma unroll
        for (int r = 0; r < kBlocks / 256; ++r)  // fixed order: deterministic
            a += partials[threadIdx.x + r * 256];
        #pragma unroll
        for (int off = 32; off > 0; off >>= 1)
            a += __shfl_down(a, off, 64);
        __shared__ float fsum[4];
        if (lane == 0) fsum[wid] = a;
        __syncthreads();
        if (threadIdx.x == 0)
            out[0] = (fsum[0] + fsum[1] + fsum[2] + fsum[3])
                     * (1.0f / (kC - 1));
    }
}

extern "C" void kernel_launch(void* const* d_in, const int* in_sizes, int n_in,
                              void* d_out, int out_size, void* d_ws, size_t ws_size,
                              hipStream_t stream) {
    const float* source          = (const float*)d_in[0];
    const int*   target          = (const int*)d_in[1];
    const int*   mask_mentions   = (const int*)d_in[2];
    const int*   mask_candidates = (const int*)d_in[3];

    float* partials = (float*)d_ws;                         // 8 KB
    int*   counters = (int*)((char*)d_ws + kBlocks * 4);    // 65 lines
    const size_t ctr_bytes = (kGroups * kCtrStride + kCtrStride) * 4;

    hipMemsetAsync(counters, 0, ctr_bytes, stream);         // zero each launch
    margin_kernel<<<kBlocks, 256, 0, stream>>>(
        source, target, mask_mentions, mask_candidates,
        partials, counters, (float*)d_out);
}

// Round 8
// 30.961 us; speedup vs baseline: 3.2250x; 3.2250x over previous
//
#include <hip/hip_runtime.h>

// MyMarginLoss: loss = sum_{b,m: mask_mentions} [ sum_c (mask_cand & c!=t) *
//                 max(0, 1.5 - (s[t] - s[c])) ] / (C-1)
// B=128, M=256, C=1024, fp32 source, int32 masks (harness-converted).
// Memory-bound: ~134.5 MB effective traffic (inactive rows never touched).
//
// R8: R2 structure (winner at 29.47us) with ONE variable: 4096 blocks x
// 8 rows (was 2048 x 16). Finer backfill granule to shrink the makespan
// tail from per-CU Binomial row-count variance, WITHOUT R6's mistake of
// shrinking the block (64-thr blocks cost 5.7us in wave residency).
// Endings learned: plain {partials -> tiny reduce kernel} beats fusion
// (R4), same-address atomics (R5: ~8ns each, serialized at tail), and
// threadfence/last-block (R7: device-scope fence = L2 flush storm on
// multi-XCD gfx950, 3.4x regression). Keep the two-kernel form.

constexpr int kC = 1024;
constexpr float kMargin = 1.5f;
constexpr int kRowsPerBlock = 8;

__global__ __launch_bounds__(256)
void margin_kernel(const float* __restrict__ source,
                   const int* __restrict__ target,
                   const int* __restrict__ mask_mentions,
                   const int* __restrict__ mask_candidates,
                   float* __restrict__ partials)
{
    const int lane = threadIdx.x & 63;
    const int wid  = threadIdx.x >> 6;
    const int row0 = blockIdx.x * kRowsPerBlock;

    // chunk metadata, loaded once per wave (redundant across waves; L2-hot)
    int flag = 0, tval = 0;
    if (lane < kRowsPerBlock) {
        flag = mask_mentions[row0 + lane];
        tval = target[row0 + lane];
    }
    const unsigned mask8 = (unsigned)(__ballot(flag != 0) & 0xFFull);

    // wave `wid` takes active rows of rank wid, wid+4, ...
    unsigned mm = mask8;
    for (int i = 0; i < wid; ++i) mm &= mm - 1;

    float acc = 0.0f;
    while (mm) {
        const int pos = __ffs(mm) - 1;          // this wave's next active row
        #pragma unroll
        for (int k = 0; k < 4; ++k) mm &= mm - 1;  // advance 4 ranks

        const int row = row0 + pos;
        const int t   = __shfl(tval, pos, 64);  // uniform broadcast, no load

        const float4* __restrict__ sp =
            reinterpret_cast<const float4*>(source + (size_t)row * kC);
        const int4*   __restrict__ mp =
            reinterpret_cast<const int4*>(mask_candidates + (size_t)row * kC);

        // 8 independent 1KB-per-wave loads; nothing else touches memory
        const float4 s0 = sp[lane],       s1 = sp[lane + 64],
                     s2 = sp[lane + 128], s3 = sp[lane + 192];
        const int4   m0 = mp[lane],       m1 = mp[lane + 64],
                     m2 = mp[lane + 128], m3 = mp[lane + 192];

        // v_t from registers: elem t lives at rep=t>>8, lane=(t>>2)&63, k=t&3
        const int rep = t >> 8, li = (t >> 2) & 63, kk = t & 3;
        const float4 sr = (rep == 0) ? s0 : (rep == 1) ? s1
                                          : (rep == 2) ? s2 : s3;   // uniform
        const float cand = (kk == 0) ? sr.x : (kk == 1) ? sr.y
                                            : (kk == 2) ? sr.z : sr.w;
        const float base = kMargin - __shfl(cand, li, 64);

        float racc = 0.0f;
        racc += (m0.x != 0) ? fmaxf(0.0f, base + s0.x) : 0.0f;
        racc += (m0.y != 0) ? fmaxf(0.0f, base + s0.y) : 0.0f;
        racc += (m0.z != 0) ? fmaxf(0.0f, base + s0.z) : 0.0f;
        racc += (m0.w != 0) ? fmaxf(0.0f, base + s0.w) : 0.0f;
        racc += (m1.x != 0) ? fmaxf(0.0f, base + s1.x) : 0.0f;
        racc += (m1.y != 0) ? fmaxf(0.0f, base + s1.y) : 0.0f;
        racc += (m1.z != 0) ? fmaxf(0.0f, base + s1.z) : 0.0f;
        racc += (m1.w != 0) ? fmaxf(0.0f, base + s1.w) : 0.0f;
        racc += (m2.x != 0) ? fmaxf(0.0f, base + s2.x) : 0.0f;
        racc += (m2.y != 0) ? fmaxf(0.0f, base + s2.y) : 0.0f;
        racc += (m2.z != 0) ? fmaxf(0.0f, base + s2.z) : 0.0f;
        racc += (m2.w != 0) ? fmaxf(0.0f, base + s2.w) : 0.0f;
        racc += (m3.x != 0) ? fmaxf(0.0f, base + s3.x) : 0.0f;
        racc += (m3.y != 0) ? fmaxf(0.0f, base + s3.y) : 0.0f;
        racc += (m3.z != 0) ? fmaxf(0.0f, base + s3.z) : 0.0f;
        racc += (m3.w != 0) ? fmaxf(0.0f, base + s3.w) : 0.0f;

        // remove the target slot's guaranteed contribution (exactly kMargin)
        if (lane == 0) racc -= kMargin;
        acc += racc;
    }

    // wave-64 butterfly + one LDS combine per block
    #pragma unroll
    for (int off = 32; off > 0; off >>= 1)
        acc += __shfl_down(acc, off, 64);

    __shared__ float wsum[4];
    if (lane == 0) wsum[wid] = acc;
    __syncthreads();
    if (threadIdx.x == 0)
        partials[blockIdx.x] = wsum[0] + wsum[1] + wsum[2] + wsum[3];
}

// Deterministic final fold of the 4096 per-block partials (16 KB, L2-hot).
__global__ __launch_bounds__(256)
void reduce_kernel(const float* __restrict__ partials, int n,
                   float* __restrict__ out)
{
    float acc = 0.0f;
    for (int i = threadIdx.x; i < n; i += 256)
        acc += partials[i];
    #pragma unroll
    for (int off = 32; off > 0; off >>= 1)
        acc += __shfl_down(acc, off, 64);
    __shared__ float wsum[4];
    const int lane = threadIdx.x & 63;
    const int wid  = threadIdx.x >> 6;
    if (lane == 0) wsum[wid] = acc;
    __syncthreads();
    if (threadIdx.x == 0)
        out[0] = (wsum[0] + wsum[1] + wsum[2] + wsum[3]) * (1.0f / (kC - 1));
}

extern "C" void kernel_launch(void* const* d_in, const int* in_sizes, int n_in,
                              void* d_out, int out_size, void* d_ws, size_t ws_size,
                              hipStream_t stream) {
    const float* source          = (const float*)d_in[0];
    const int*   target          = (const int*)d_in[1];
    const int*   mask_mentions   = (const int*)d_in[2];
    const int*   mask_candidates = (const int*)d_in[3];
    const int n_rows = in_sizes[1];                  // B*M = 32768
    const int n_blocks = n_rows / kRowsPerBlock;     // 4096
    float* partials = (float*)d_ws;                  // 16 KB scratch

    margin_kernel<<<n_blocks, 256, 0, stream>>>(
        source, target, mask_mentions, mask_candidates, partials);
    reduce_kernel<<<1, 256, 0, stream>>>(partials, n_blocks, (float*)d_out);
}

// Round 9
// 28.336 us; speedup vs baseline: 3.5238x; 1.0927x over previous
//
#include <hip/hip_runtime.h>

// MyMarginLoss: loss = sum_{b,m: mask_mentions} [ sum_c (mask_cand & c!=t) *
//                 max(0, 1.5 - (s[t] - s[c])) ] / (C-1)
// B=128, M=256, C=1024, fp32 source, int32 masks (harness-converted).
// Memory-bound: ~134.5 MB effective traffic (inactive rows never touched).
//
// FINAL (== R2, the measured optimum at 29.47us over 8 structural probes):
//   main: 2048 blocks x 256 thr, 16 rows/block; waves split the block's
//   ACTIVE rows via ballot+bit-walk; per active row the only memory ops are
//   8 coalesced 1KB vector loads (source float4 + mask int4).
//   ending: per-block partial -> separate 1-block reduce kernel.
// Probed and rejected: 1/4/8/64-row blocks (R1/R6/R8/R4: +1.5..5.9us),
// nt-loads (R4), same-address atomicAdd (R5: ~8ns serialized each),
// threadfence last-block reduction (R7: device-scope fence = cross-XCD L2
// flush storm, 3.4x), v_t-from-registers + active-row rebalance (R3:
// neutral). Accounting: main 26.5us = 134.5MB @ ~5.2 TB/s (83% of dense
// m13 copy rate, 50%-dense 8KB-granule pattern) + ~3us two-dispatch tail.

constexpr int kC = 1024;
constexpr float kMargin = 1.5f;
constexpr int kRowsPerBlock = 16;

__global__ __launch_bounds__(256)
void margin_kernel(const float* __restrict__ source,
                   const int* __restrict__ target,
                   const int* __restrict__ mask_mentions,
                   const int* __restrict__ mask_candidates,
                   float* __restrict__ partials)
{
    const int lane = threadIdx.x & 63;
    const int wid  = threadIdx.x >> 6;
    const int row0 = blockIdx.x * kRowsPerBlock;

    // chunk metadata, loaded once per wave (redundant across waves; L2-hot)
    int flag = 0, tval = 0;
    if (lane < kRowsPerBlock) {
        flag = mask_mentions[row0 + lane];
        tval = target[row0 + lane];
    }
    const unsigned mask16 = (unsigned)(__ballot(flag != 0) & 0xFFFFull);

    // wave `wid` takes active rows of rank wid, wid+4, wid+8, ...
    unsigned mm = mask16;
    for (int i = 0; i < wid; ++i) mm &= mm - 1;

    float acc = 0.0f;
    while (mm) {
        const int pos = __ffs(mm) - 1;          // this wave's next active row
        #pragma unroll
        for (int k = 0; k < 4; ++k) mm &= mm - 1;  // advance 4 ranks

        const int row = row0 + pos;
        const int t   = __shfl(tval, pos, 64);  // uniform broadcast, no load

        const float* __restrict__ srow = source + (size_t)row * kC;
        const float4* __restrict__ sp  = reinterpret_cast<const float4*>(srow);
        const int4*   __restrict__ mp  =
            reinterpret_cast<const int4*>(mask_candidates + (size_t)row * kC);
        const float v_t = srow[t];              // same-address wave load

        // 8 independent 1KB-per-wave loads; nothing else touches memory
        const float4 s0 = sp[lane],       s1 = sp[lane + 64],
                     s2 = sp[lane + 128], s3 = sp[lane + 192];
        const int4   m0 = mp[lane],       m1 = mp[lane + 64],
                     m2 = mp[lane + 128], m3 = mp[lane + 192];

        const float base = kMargin - v_t;

        float racc = 0.0f;
        const int base_c = lane * 4;
        racc += (m0.x != 0 && (base_c +   0) != t) ? fmaxf(0.0f, base + s0.x) : 0.0f;
        racc += (m0.y != 0 && (base_c +   1) != t) ? fmaxf(0.0f, base + s0.y) : 0.0f;
        racc += (m0.z != 0 && (base_c +   2) != t) ? fmaxf(0.0f, base + s0.z) : 0.0f;
        racc += (m0.w != 0 && (base_c +   3) != t) ? fmaxf(0.0f, base + s0.w) : 0.0f;
        racc += (m1.x != 0 && (base_c + 256) != t) ? fmaxf(0.0f, base + s1.x) : 0.0f;
        racc += (m1.y != 0 && (base_c + 257) != t) ? fmaxf(0.0f, base + s1.y) : 0.0f;
        racc += (m1.z != 0 && (base_c + 258) != t) ? fmaxf(0.0f, base + s1.z) : 0.0f;
        racc += (m1.w != 0 && (base_c + 259) != t) ? fmaxf(0.0f, base + s1.w) : 0.0f;
        racc += (m2.x != 0 && (base_c + 512) != t) ? fmaxf(0.0f, base + s2.x) : 0.0f;
        racc += (m2.y != 0 && (base_c + 513) != t) ? fmaxf(0.0f, base + s2.y) : 0.0f;
        racc += (m2.z != 0 && (base_c + 514) != t) ? fmaxf(0.0f, base + s2.z) : 0.0f;
        racc += (m2.w != 0 && (base_c + 515) != t) ? fmaxf(0.0f, base + s2.w) : 0.0f;
        racc += (m3.x != 0 && (base_c + 768) != t) ? fmaxf(0.0f, base + s3.x) : 0.0f;
        racc += (m3.y != 0 && (base_c + 769) != t) ? fmaxf(0.0f, base + s3.y) : 0.0f;
        racc += (m3.z != 0 && (base_c + 770) != t) ? fmaxf(0.0f, base + s3.z) : 0.0f;
        racc += (m3.w != 0 && (base_c + 771) != t) ? fmaxf(0.0f, base + s3.w) : 0.0f;

        acc += racc;
    }

    // wave-64 butterfly + one LDS combine per block
    #pragma unroll
    for (int off = 32; off > 0; off >>= 1)
        acc += __shfl_down(acc, off, 64);

    __shared__ float wsum[4];
    if (lane == 0) wsum[wid] = acc;
    __syncthreads();
    if (threadIdx.x == 0)
        partials[blockIdx.x] = wsum[0] + wsum[1] + wsum[2] + wsum[3];
}

// Deterministic final fold of the 2048 per-block partials (8 KB, L2-hot).
__global__ __launch_bounds__(256)
void reduce_kernel(const float* __restrict__ partials, int n,
                   float* __restrict__ out)
{
    float acc = 0.0f;
    for (int i = threadIdx.x; i < n; i += 256)
        acc += partials[i];
    #pragma unroll
    for (int off = 32; off > 0; off >>= 1)
        acc += __shfl_down(acc, off, 64);
    __shared__ float wsum[4];
    const int lane = threadIdx.x & 63;
    const int wid  = threadIdx.x >> 6;
    if (lane == 0) wsum[wid] = acc;
    __syncthreads();
    if (threadIdx.x == 0)
        out[0] = (wsum[0] + wsum[1] + wsum[2] + wsum[3]) * (1.0f / (kC - 1));
}

extern "C" void kernel_launch(void* const* d_in, const int* in_sizes, int n_in,
                              void* d_out, int out_size, void* d_ws, size_t ws_size,
                              hipStream_t stream) {
    const float* source          = (const float*)d_in[0];
    const int*   target          = (const int*)d_in[1];
    const int*   mask_mentions   = (const int*)d_in[2];
    const int*   mask_candidates = (const int*)d_in[3];
    const int n_rows = in_sizes[1];                  // B*M = 32768
    const int n_blocks = n_rows / kRowsPerBlock;     // 2048
    float* partials = (float*)d_ws;                  // 8 KB scratch

    margin_kernel<<<n_blocks, 256, 0, stream>>>(
        source, target, mask_mentions, mask_candidates, partials);
    reduce_kernel<<<1, 256, 0, stream>>>(partials, n_blocks, (float*)d_out);
}